// Round 2
// baseline (1476.225 us; speedup 1.0000x reference)
//
#include <hip/hip_runtime.h>

#define BIGV 1e10f

typedef unsigned short ushort_t;
typedef __attribute__((ext_vector_type(8))) short short8;
typedef __attribute__((ext_vector_type(4))) float f32x4;

constexpr int B_ = 64, L_ = 1024, C_ = 64;
constexpr int TN = 16;   // 64x64 tiles per dimension
constexpr int NW = 16;   // waves per block
constexpr int DSTR = 72; // Dt row stride (ushorts): 2-way banks on read AND write

static __device__ inline ushort_t f2bf(float f) {
  unsigned u = __builtin_bit_cast(unsigned, f);
  unsigned r = (u + 0x7fffu + ((u >> 16) & 1u)) >> 16;
  return (ushort_t)r;
}
static __device__ inline float bf2f(ushort_t us) {
  return __builtin_bit_cast(float, ((unsigned)us) << 16);
}
static __device__ inline float wave_shr1(float v) {
  // lane i <- lane i-1; lane 0 keeps old (we pass v as old; overridden anyway)
  return __builtin_bit_cast(float, __builtin_amdgcn_update_dpp(
      __builtin_bit_cast(int, v), __builtin_bit_cast(int, v),
      0x138 /*wave_shr:1*/, 0xF, 0xF, false));
}
static __device__ inline float bcast_lane(float v, int lane) {
  return __builtin_bit_cast(float,
      __builtin_amdgcn_readlane(__builtin_bit_cast(int, v), lane));
}

// Pass 1: convert x,y to bf16 (RNE) and compute row squared-norms in fp32.
__global__ __launch_bounds__(256) void prep_kernel(
    const float* __restrict__ x, const float* __restrict__ y,
    ushort_t* __restrict__ xb, ushort_t* __restrict__ yb,
    float* __restrict__ x2, float* __restrict__ y2)
{
  const int lane = threadIdx.x & 63;
  const int waveg = (blockIdx.x * blockDim.x + threadIdx.x) >> 6;
  const int totalWaves = (gridDim.x * blockDim.x) >> 6;
  const int totalRows = 2 * B_ * L_;
  for (int row = waveg; row < totalRows; row += totalWaves) {
    const float* src; ushort_t* dst; float* nrm; int r;
    if (row < B_ * L_) { r = row;            src = x; dst = xb; nrm = x2; }
    else               { r = row - B_ * L_;  src = y; dst = yb; nrm = y2; }
    float v = src[r * C_ + lane];           // C_ == 64 == wave width
    dst[r * C_ + lane] = f2bf(v);
    float s = v * v;
    #pragma unroll
    for (int off = 32; off > 0; off >>= 1) s += __shfl_down(s, off);
    if (lane == 0) nrm[r] = s;
  }
}

// Pass 2: one block per batch, tile-wavefront soft-DTW.
// DP inner loop: single DPP wave_shr per step (diag = prev step's shifted
// value), top-row via preloaded register + readlane broadcast, bottom-row via
// address-selected ds_write (no exec churn), right-column deferred to
// post-loop (frozen cur == cell(r,63)).
__global__ __launch_bounds__(1024) void sdtw_kernel(
    const ushort_t* __restrict__ xb, const ushort_t* __restrict__ yb,
    const float* __restrict__ x2g, const float* __restrict__ y2g,
    float* __restrict__ out)
{
  __shared__ ushort_t Dt[NW][64 * DSTR];
  __shared__ float Hbuf[L_];
  __shared__ float Vbuf[L_];
  __shared__ float CC[2][TN + 1];
  __shared__ float dummyw;

  const int b = blockIdx.x;
  const int w = threadIdx.x >> 6;
  const int lane = threadIdx.x & 63;
  const int m = lane & 15, q = lane >> 4;
  const bool is0 = (lane == 0);
  const bool is63 = (lane == 63);

  const ushort_t* xbB = xb + (size_t)b * L_ * C_;
  const ushort_t* ybB = yb + (size_t)b * L_ * C_;
  const float* x2B = x2g + b * L_;
  const float* y2B = y2g + b * L_;

  for (int t = 0; t < 2 * TN - 1; ++t) {
    int tiLo = t - (TN - 1); if (tiLo < 0) tiLo = 0;
    int tiHi = (t < TN) ? t : TN - 1;
    const bool act = (w < tiHi - tiLo + 1);
    const int ti = tiLo + w;
    const int tj = t - ti;
    const int i0 = ti * 64, j0 = tj * 64;

    // ---- read phase: boundaries written in round t-1 (pre-barrier) ----
    float cornerIn = BIGV, vleft = BIGV, hreg = BIGV;
    if (act) {
      if (ti == 0)      cornerIn = (tj == 0) ? 0.0f : BIGV;
      else if (tj == 0) cornerIn = BIGV;
      else              cornerIn = CC[ti & 1][tj];
      if (tj > 0) vleft = Vbuf[i0 + lane];
      if (ti > 0) hreg = Hbuf[j0 + lane];
    }
    float diag0 = __shfl_up(vleft, 1);
    if (is0) diag0 = cornerIn;
    __syncthreads();

    if (act) {
      // ---- Gram tile: G = x_tile . y_tile^T (bf16 MFMA) ----
      short8 af[4][2], bfr[4][2];
      #pragma unroll
      for (int mt = 0; mt < 4; ++mt) {
        #pragma unroll
        for (int ks = 0; ks < 2; ++ks) {
          af[mt][ks]  = *(const short8*)(xbB + (size_t)(i0 + mt * 16 + m) * C_ + ks * 32 + q * 8);
          bfr[mt][ks] = *(const short8*)(ybB + (size_t)(j0 + mt * 16 + m) * C_ + ks * 32 + q * 8);
        }
      }
      #pragma unroll
      for (int mt = 0; mt < 4; ++mt) {
        f32x4 x2v = *(const f32x4*)(x2B + i0 + mt * 16 + q * 4);
        #pragma unroll
        for (int nt = 0; nt < 4; ++nt) {
          f32x4 acc = {0.f, 0.f, 0.f, 0.f};
          acc = __builtin_amdgcn_mfma_f32_16x16x32_bf16(af[mt][0], bfr[nt][0], acc, 0, 0, 0);
          acc = __builtin_amdgcn_mfma_f32_16x16x32_bf16(af[mt][1], bfr[nt][1], acc, 0, 0, 0);
          float y2v = y2B[j0 + nt * 16 + m];
          #pragma unroll
          for (int reg = 0; reg < 4; ++reg) {
            float d = x2v[reg] + y2v - 2.0f * acc[reg];
            // C/D layout: row = q*4+reg, col = m  (verified m89)
            Dt[w][(mt * 16 + q * 4 + reg) * DSTR + nt * 16 + m] = f2bf(d);
          }
        }
      }

      // ---- in-register systolic DP over the 64x64 tile ----
      const int r = lane;
      float cur = 0.f, up_old = 0.f, hv_last = BIGV;
      float* dumaddr = &dummyw;
      #pragma unroll 2
      for (int s = 0; s < 127; ++s) {
        float hv = bcast_lane(hreg, s & 63);      // off-chain (scalar bcast)
        float sh = wave_shr1(cur);                // the ONE cross-lane op on chain
        int c = s - r;
        bool c0 = (c == 0);
        float up = is0 ? hv : sh;
        float dg = is0 ? hv_last : up_old;
        dg = c0 ? diag0 : dg;
        float lf = c0 ? vleft : cur;
        float dv = bf2f(Dt[w][r * DSTR + (c & 63)]);  // off-chain, prefetchable
        float mn = fminf(fminf(up, dg), lf);
        float e = __expf(mn - up) + __expf(mn - dg) + __expf(mn - lf);
        float nv = dv + (mn - __logf(e));
        up_old = up;
        hv_last = hv;
        cur = ((unsigned)c < 64u) ? nv : cur;
        // bottom row -> Hbuf for the tile below; others hit the dummy word
        float* haddr = (is63 && s >= 63) ? &Hbuf[j0 + (s - 63)] : dumaddr;
        *haddr = cur;
      }
      Vbuf[i0 + r] = cur;                        // frozen cur == cell(r, 63)
      if (is63) {
        CC[(ti + 1) & 1][tj + 1] = cur;          // bottom-right corner
        if (ti == TN - 1 && tj == TN - 1) out[b] = cur;  // R[L-1][L-1], gamma=1
      }
    }
    __syncthreads();
  }
}

extern "C" void kernel_launch(void* const* d_in, const int* in_sizes, int n_in,
                              void* d_out, int out_size, void* d_ws, size_t ws_size,
                              hipStream_t stream) {
  const float* x = (const float*)d_in[0];
  const float* y = (const float*)d_in[1];
  float* out = (float*)d_out;

  // ws layout: xb (8MB) | yb (8MB) | x2 (256KB) | y2 (256KB)
  char* ws = (char*)d_ws;
  ushort_t* xb = (ushort_t*)ws;
  ushort_t* yb = (ushort_t*)(ws + (size_t)B_ * L_ * C_ * 2);
  float* x2 = (float*)(ws + (size_t)B_ * L_ * C_ * 4);
  float* y2 = (float*)(ws + (size_t)B_ * L_ * C_ * 4 + (size_t)B_ * L_ * 4);

  prep_kernel<<<512, 256, 0, stream>>>(x, y, xb, yb, x2, y2);
  sdtw_kernel<<<B_, 1024, 0, stream>>>(xb, yb, x2, y2, out);
}

// Round 3
// 1232.847 us; speedup vs baseline: 1.1974x; 1.1974x over previous
//
#include <hip/hip_runtime.h>

#define BIGV 1e10f

typedef unsigned short ushort_t;
typedef __attribute__((ext_vector_type(8))) short short8;
typedef __attribute__((ext_vector_type(4))) float f32x4;

constexpr int B_ = 64, L_ = 1024, C_ = 64;
constexpr int TN = 16;   // 64x64 tiles per dimension
constexpr int NW = 16;   // waves per block
constexpr int DSTR = 72; // Dt row stride (ushorts)

// unified float shared array offsets (so conditional stores stay addrspace(3))
constexpr int HOFF = 0;          // Hbuf[1024]
constexpr int VOFF = 1024;       // Vbuf[1024]
constexpr int COFF = 2048;       // CC[2][17] -> 34, padded
constexpr int DOFF = 2112;       // dump[16][64]
constexpr int SHF_N = 2112 + NW * 64;   // 3136 floats = 12544 B

static __device__ inline ushort_t f2bf(float f) {
  unsigned u = __builtin_bit_cast(unsigned, f);
  unsigned r = (u + 0x7fffu + ((u >> 16) & 1u)) >> 16;
  return (ushort_t)r;
}
static __device__ inline float bf2f(ushort_t us) {
  return __builtin_bit_cast(float, ((unsigned)us) << 16);
}
static __device__ inline float wave_shr1(float v) {
  // lane i <- lane i-1 (lane 0 garbage; overridden by cndmask)
  return __builtin_bit_cast(float, __builtin_amdgcn_update_dpp(
      __builtin_bit_cast(int, v), __builtin_bit_cast(int, v),
      0x138 /*wave_shr:1*/, 0xF, 0xF, false));
}
static __device__ inline float bcast_lane(float v, int lane) {
  return __builtin_bit_cast(float,
      __builtin_amdgcn_readlane(__builtin_bit_cast(int, v), lane));
}

// Pass 1: convert x,y to bf16 (RNE) and compute row squared-norms in fp32.
__global__ __launch_bounds__(256) void prep_kernel(
    const float* __restrict__ x, const float* __restrict__ y,
    ushort_t* __restrict__ xb, ushort_t* __restrict__ yb,
    float* __restrict__ x2, float* __restrict__ y2)
{
  const int lane = threadIdx.x & 63;
  const int waveg = (blockIdx.x * blockDim.x + threadIdx.x) >> 6;
  const int totalWaves = (gridDim.x * blockDim.x) >> 6;
  const int totalRows = 2 * B_ * L_;
  for (int row = waveg; row < totalRows; row += totalWaves) {
    const float* src; ushort_t* dst; float* nrm; int r;
    if (row < B_ * L_) { r = row;            src = x; dst = xb; nrm = x2; }
    else               { r = row - B_ * L_;  src = y; dst = yb; nrm = y2; }
    float v = src[r * C_ + lane];           // C_ == 64 == wave width
    dst[r * C_ + lane] = f2bf(v);
    float s = v * v;
    #pragma unroll
    for (int off = 32; off > 0; off >>= 1) s += __shfl_down(s, off);
    if (lane == 0) nrm[r] = s;
  }
}

// Pass 2: one block per batch, tile-wavefront soft-DTW.
__global__ __launch_bounds__(1024) void sdtw_kernel(
    const ushort_t* __restrict__ xb, const ushort_t* __restrict__ yb,
    const float* __restrict__ x2g, const float* __restrict__ y2g,
    float* __restrict__ out)
{
  __shared__ ushort_t Dt[NW][64 * DSTR];   // 147456 B
  __shared__ float ShF[SHF_N];             // 12544 B  (total 160000 <= 163840)

  const int b = blockIdx.x;
  const int w = threadIdx.x >> 6;
  const int lane = threadIdx.x & 63;
  const int m = lane & 15, q = lane >> 4;
  const bool is0 = (lane == 0);
  const bool is63 = (lane == 63);

  const ushort_t* xbB = xb + (size_t)b * L_ * C_;
  const ushort_t* ybB = yb + (size_t)b * L_ * C_;
  const float* x2B = x2g + b * L_;
  const float* y2B = y2g + b * L_;

  for (int t = 0; t < 2 * TN - 1; ++t) {
    int tiLo = t - (TN - 1); if (tiLo < 0) tiLo = 0;
    int tiHi = (t < TN) ? t : TN - 1;
    const bool act = (w < tiHi - tiLo + 1);
    const int ti = tiLo + w;
    const int tj = t - ti;
    const int i0 = ti * 64, j0 = tj * 64;

    // ---- read phase: boundaries written in round t-1 (pre-barrier) ----
    float cornerIn = BIGV, vleft = BIGV, hreg = BIGV;
    if (act) {
      if (ti == 0)      cornerIn = (tj == 0) ? 0.0f : BIGV;
      else if (tj == 0) cornerIn = BIGV;
      else              cornerIn = ShF[COFF + (ti & 1) * 17 + tj];
      if (tj > 0) vleft = ShF[VOFF + i0 + lane];
      if (ti > 0) hreg = ShF[HOFF + j0 + lane];
    }
    float diag0 = __shfl_up(vleft, 1);
    if (is0) diag0 = cornerIn;
    __syncthreads();

    if (act) {
      // ---- Gram tile (operands swapped: A=y rows, B=x rows) so the 4
      //      accumulator regs are consecutive in the stored row -> b64 pack.
      //      C[row=q*4+reg][col=m] = y_{j0+mt*16+q*4+reg} . x_{i0+nt*16+m}
      //      = D[i=i0+nt*16+m][j=j0+mt*16+q*4+reg]
      short8 af[4][2], bfr[4][2];
      #pragma unroll
      for (int mt = 0; mt < 4; ++mt) {
        #pragma unroll
        for (int ks = 0; ks < 2; ++ks) {
          af[mt][ks]  = *(const short8*)(ybB + (size_t)(j0 + mt * 16 + m) * C_ + ks * 32 + q * 8);
          bfr[mt][ks] = *(const short8*)(xbB + (size_t)(i0 + mt * 16 + m) * C_ + ks * 32 + q * 8);
        }
      }
      #pragma unroll
      for (int mt = 0; mt < 4; ++mt) {
        f32x4 y2v = *(const f32x4*)(y2B + j0 + mt * 16 + q * 4);
        #pragma unroll
        for (int nt = 0; nt < 4; ++nt) {
          f32x4 acc = {0.f, 0.f, 0.f, 0.f};
          acc = __builtin_amdgcn_mfma_f32_16x16x32_bf16(af[mt][0], bfr[nt][0], acc, 0, 0, 0);
          acc = __builtin_amdgcn_mfma_f32_16x16x32_bf16(af[mt][1], bfr[nt][1], acc, 0, 0, 0);
          float x2v = x2B[i0 + nt * 16 + m];
          float d0 = x2v + y2v[0] - 2.0f * acc[0];
          float d1 = x2v + y2v[1] - 2.0f * acc[1];
          float d2 = x2v + y2v[2] - 2.0f * acc[2];
          float d3 = x2v + y2v[3] - 2.0f * acc[3];
          unsigned lo = (unsigned)f2bf(d0) | ((unsigned)f2bf(d1) << 16);
          unsigned hi = (unsigned)f2bf(d2) | ((unsigned)f2bf(d3) << 16);
          uint2 pk; pk.x = lo; pk.y = hi;
          // row r = nt*16+m, cols mt*16+q*4 .. +3
          *(uint2*)&Dt[w][(nt * 16 + m) * DSTR + mt * 16 + q * 4] = pk;
        }
      }

      // ---- in-register systolic DP over the 64x64 tile ----
      const int r = lane;
      const ushort_t* Drow = &Dt[w][r * DSTR];
      float cur = 0.f, up_old = 0.f, hv_last = BIGV;
      int c = -r;
      float dv_next = bf2f(Drow[(-r) & 63]);
      float hv_next = bcast_lane(hreg, 0);
      #pragma unroll 1
      for (int s = 0; s < 127; ++s) {
        float dv = dv_next, hv = hv_next;
        // prefetch step s+1 (off the dependency chain)
        dv_next = bf2f(Drow[(s + 1 - r) & 63]);
        hv_next = bcast_lane(hreg, (s + 1) & 63);
        float sh = wave_shr1(cur);              // the ONE cross-lane op on chain
        bool c0 = (c == 0);
        float up = is0 ? hv : sh;
        float dg = is0 ? hv_last : up_old;
        dg = c0 ? diag0 : dg;
        float lf = c0 ? vleft : cur;
        float p  = fminf(up, dg);
        float q2 = fmaxf(up, dg);
        float mn = fminf(p, lf);
        float o1 = fmaxf(p, lf);
        float e  = 1.0f + __expf(mn - o1) + __expf(mn - q2);  // exp(0)=1 folded
        float nv = dv + (mn - __logf(e));
        up_old = up;
        hv_last = hv;
        cur = ((unsigned)c < 64u) ? nv : cur;
        // lane 63, steps 63..126 -> Hbuf[j0 + s-63]; everyone else -> dump slot
        int sidx = (is63 && s >= 63) ? (HOFF + j0 + (s - 63)) : (DOFF + (w << 6) + r);
        ShF[sidx] = cur;
        ++c;
      }
      ShF[VOFF + i0 + r] = cur;                 // frozen cur == cell(r, 63)
      if (is63) {
        ShF[COFF + ((ti + 1) & 1) * 17 + (tj + 1)] = cur;   // corner
        if (ti == TN - 1 && tj == TN - 1) out[b] = cur;     // R[L-1][L-1]
      }
    }
    __syncthreads();
  }
}

extern "C" void kernel_launch(void* const* d_in, const int* in_sizes, int n_in,
                              void* d_out, int out_size, void* d_ws, size_t ws_size,
                              hipStream_t stream) {
  const float* x = (const float*)d_in[0];
  const float* y = (const float*)d_in[1];
  float* out = (float*)d_out;

  // ws layout: xb (8MB) | yb (8MB) | x2 (256KB) | y2 (256KB)
  char* ws = (char*)d_ws;
  ushort_t* xb = (ushort_t*)ws;
  ushort_t* yb = (ushort_t*)(ws + (size_t)B_ * L_ * C_ * 2);
  float* x2 = (float*)(ws + (size_t)B_ * L_ * C_ * 4);
  float* y2 = (float*)(ws + (size_t)B_ * L_ * C_ * 4 + (size_t)B_ * L_ * 4);

  prep_kernel<<<512, 256, 0, stream>>>(x, y, xb, yb, x2, y2);
  sdtw_kernel<<<B_, 1024, 0, stream>>>(xb, yb, x2, y2, out);
}